// Round 3
// baseline (338.399 us; speedup 1.0000x reference)
//
#include <hip/hip_runtime.h>
#include <hip/hip_bf16.h>

// Problem constants (BLoraLinear): T=8192, D_IN=4096, D_OUT=4096, R=16, M=2, S=8
#define T_TOK 8192
#define DIN   4096
#define DOUT  4096
#define RANK  16
#define NMOD  2
#define NSEG  8

typedef __attribute__((ext_vector_type(8))) short bf16x8;
typedef __attribute__((ext_vector_type(8))) unsigned short u16x8;
typedef __attribute__((ext_vector_type(4))) float f32x4;

__device__ inline unsigned short f2bf(float f) {
    union { float f; unsigned u; } v; v.f = f;
    unsigned r = v.u + 0x7FFFu + ((v.u >> 16) & 1u);   // RNE
    return (unsigned short)(r >> 16);
}

__device__ inline void gload_lds16(const void* g, void* l) {
    __builtin_amdgcn_global_load_lds(
        (const __attribute__((address_space(1))) void*)g,
        (__attribute__((address_space(3))) void*)l, 16, 0, 0);
}

// ---------------- fp32 -> bf16 cast (vectorized, 8 elems/thread) -------------
__global__ void cast_bf16_kernel(const float* __restrict__ src,
                                 unsigned short* __restrict__ dst, int n8) {
    int i = blockIdx.x * blockDim.x + threadIdx.x;
    if (i >= n8) return;
    const float4* s4 = (const float4*)src;
    float4 a = s4[2 * (size_t)i];
    float4 b = s4[2 * (size_t)i + 1];
    u16x8 o;
    o[0] = f2bf(a.x); o[1] = f2bf(a.y); o[2] = f2bf(a.z); o[3] = f2bf(a.w);
    o[4] = f2bf(b.x); o[5] = f2bf(b.y); o[6] = f2bf(b.z); o[7] = f2bf(b.w);
    *(u16x8*)(dst + 8 * (size_t)i) = o;
}

// ---------- At[s][m*16+r][d] = lora_A[m][s][d][r]  (bf16) --------------------
__global__ void prep_A_kernel(const float* __restrict__ A,
                              unsigned short* __restrict__ At) {
    int idx = blockIdx.x * 256 + threadIdx.x;     // NSEG*32*DIN total
    int d   = idx & (DIN - 1);
    int smr = idx >> 12;
    int s   = smr >> 5, mr = smr & 31;
    int m   = mr >> 4,  r  = mr & 15;
    float v = A[(((size_t)(m * NSEG + s) * DIN) + d) * RANK + r];
    At[idx] = f2bf(v);
}

// ---------- Bt[s][o][m*16+r] = lora_B[m][s][r][o]  (bf16) --------------------
__global__ void prep_B_kernel(const float* __restrict__ B,
                              unsigned short* __restrict__ Bt) {
    int o  = blockIdx.x * 256 + threadIdx.x;      // NSEG*DOUT total
    int s  = o >> 12;
    int oc = o & (DOUT - 1);
    unsigned short tmp[32];
    for (int m = 0; m < NMOD; ++m)
        for (int r = 0; r < RANK; ++r)
            tmp[m * 16 + r] =
                f2bf(B[(((size_t)(m * NSEG + s) * RANK) + r) * DOUT + oc]);
    for (int k = 0; k < 4; ++k) {
        u16x8 v;
        for (int j = 0; j < 8; ++j) v[j] = tmp[k * 8 + j];
        *(u16x8*)(Bt + (size_t)o * 32 + k * 8) = v;
    }
}

// ---------- u partials: Pu[ky][t][mr] = sum_{k in split} x[t,k]*At[s(t)][mr][k]
__global__ __launch_bounds__(64) void u_gemm_kernel(
    const unsigned short* __restrict__ xb, const unsigned short* __restrict__ At,
    const int* __restrict__ cu, float* __restrict__ Pu) {
    int tile = blockIdx.x;          // 0..255
    int ky   = blockIdx.y;          // 0..3
    int lane = threadIdx.x;
    int l15  = lane & 15, lk = lane >> 4;
    int t0   = tile * 32;
    f32x4 acc[2][2] = {};
    bf16x8 zero = {};
    for (int s = 0; s < NSEG; ++s) {
        int lo = cu[s], hi = cu[s + 1];
        if (hi <= t0 || lo >= t0 + 32) continue;
        const unsigned short* atb = At + (size_t)(s * 32) * DIN;
        for (int kt = 0; kt < 32; ++kt) {
            int k0 = ky * 1024 + kt * 32 + lk * 8;
            bf16x8 a[2], b[2];
            for (int mi = 0; mi < 2; ++mi) {
                int row = t0 + mi * 16 + l15;
                bf16x8 av = *(const bf16x8*)(xb + (size_t)row * DIN + k0);
                a[mi] = (row >= lo && row < hi) ? av : zero;
            }
            for (int ni = 0; ni < 2; ++ni) {
                int mr = ni * 16 + l15;
                b[ni] = *(const bf16x8*)(atb + (size_t)mr * DIN + k0);
            }
            for (int mi = 0; mi < 2; ++mi)
                for (int ni = 0; ni < 2; ++ni)
                    acc[mi][ni] = __builtin_amdgcn_mfma_f32_16x16x32_bf16(
                        a[mi], b[ni], acc[mi][ni], 0, 0, 0);
        }
    }
    for (int mi = 0; mi < 2; ++mi)
        for (int ni = 0; ni < 2; ++ni)
            for (int j = 0; j < 4; ++j) {
                int t  = t0 + mi * 16 + lk * 4 + j;
                int mr = ni * 16 + l15;
                Pu[((size_t)ky * T_TOK + t) * 32 + mr] = acc[mi][ni][j];
            }
}

// ---------- reduce 4 K-split partials -> ub bf16 [T][32] ---------------------
__global__ void reduce_u_kernel(const float* __restrict__ Pu,
                                unsigned short* __restrict__ ub) {
    int idx = blockIdx.x * 256 + threadIdx.x;   // T_TOK*32
    const size_t STRIDE = (size_t)T_TOK * 32;
    float s = Pu[idx] + Pu[idx + STRIDE] + Pu[idx + 2 * STRIDE] + Pu[idx + 3 * STRIDE];
    ub[idx] = f2bf(s);
}

// ============================================================================
// Main GEMM: 256x256 tile, BK=32, 8 waves (2Mx4N), ring-of-4 LDS (128 KiB),
// prefetch distance 3 K-tiles, counted vmcnt(8) once per K-tile (never 0 in
// the main loop), XOR-swizzled LDS (verified conflict-free: SQ_LDS_BANK_
// CONFLICT = 0), m201-style per-phase lockstep:
//   { ds_read frags ; issue stage gloads ; s_barrier ; lgkmcnt(0) ;
//     sched_barrier(0) ; setprio(1) ; 16 MFMA ; setprio(0) ; s_barrier }
// Two phases per K-tile (acc rows 0-3 / 4-7), vmcnt counted in phase B.
// ============================================================================

__device__ __forceinline__ bf16x8 lds_frag(const char* tile, int row, int lk) {
    int rb = (row << 6) + (lk << 4);
    rb ^= ((rb >> 7) & 7) << 4;
    return *(const bf16x8*)(tile + rb);
}

// stage one 8 KiB chunk (512 threads x 16 B) of a [256][32] bf16 tile half
__device__ __forceinline__ void stage_chunk(const unsigned short* gbase,
                                            char* lds_tile, int chunkbase, int tid) {
    int tb = chunkbase + tid * 16;
    int gb = tb ^ (((tb >> 7) & 7) << 4);
    int row = gb >> 6;
    int col = (gb & 63) >> 1;
    gload_lds16(gbase + (size_t)row * DIN + col, lds_tile + tb);
}

#define KTILE_BODY(T_, STG_, VM_)                                              \
  {                                                                            \
    const int t_ = (T_);                                                       \
    const char* Asl = lds + (t_ & 3) * 32768;                                  \
    const char* Bsl = Asl + 16384;                                             \
    bf16x8 bfr[4], af[4];                                                      \
    /* ---------------- phase A ---------------- */                            \
    for (int n = 0; n < 4; ++n)                                                \
        bfr[n] = lds_frag(Bsl, wcol + n * 16 + l15, lk);                       \
    for (int m = 0; m < 4; ++m)                                                \
        af[m] = lds_frag(Asl, wrow + m * 16 + l15, lk);                        \
    if (STG_) {                                                                \
        int k0s = (t_ + 3) * 32;                                               \
        char* dst = lds + ((t_ + 3) & 3) * 32768;                              \
        stage_chunk(xrow + k0s, dst, 0, tid);                                  \
        stage_chunk(xrow + k0s, dst, 8192, tid);                               \
    }                                                                          \
    __builtin_amdgcn_s_barrier();                                              \
    asm volatile("s_waitcnt lgkmcnt(0)" ::: "memory");                         \
    __builtin_amdgcn_sched_barrier(0);                                         \
    __builtin_amdgcn_s_setprio(1);                                             \
    for (int m = 0; m < 4; ++m)                                                \
        for (int n = 0; n < 4; ++n)                                            \
            acc[m][n] = __builtin_amdgcn_mfma_f32_16x16x32_bf16(               \
                af[m], bfr[n], acc[m][n], 0, 0, 0);                            \
    __builtin_amdgcn_s_setprio(0);                                             \
    __builtin_amdgcn_s_barrier();                                              \
    /* ---------------- phase B ---------------- */                            \
    for (int m = 0; m < 4; ++m)                                                \
        af[m] = lds_frag(Asl, wrow + (4 + m) * 16 + l15, lk);                  \
    if (STG_) {                                                                \
        int k0s = (t_ + 3) * 32;                                               \
        char* dst = lds + ((t_ + 3) & 3) * 32768 + 16384;                      \
        stage_chunk(wrow_g + k0s, dst, 0, tid);                                \
        stage_chunk(wrow_g + k0s, dst, 8192, tid);                             \
    }                                                                          \
    if ((VM_) == 8)      asm volatile("s_waitcnt vmcnt(8)" ::: "memory");      \
    else if ((VM_) == 4) asm volatile("s_waitcnt vmcnt(4)" ::: "memory");      \
    else if ((VM_) == 0) asm volatile("s_waitcnt vmcnt(0)" ::: "memory");      \
    __builtin_amdgcn_s_barrier();                                              \
    asm volatile("s_waitcnt lgkmcnt(0)" ::: "memory");                         \
    __builtin_amdgcn_sched_barrier(0);                                         \
    __builtin_amdgcn_s_setprio(1);                                             \
    for (int m = 0; m < 4; ++m)                                                \
        for (int n = 0; n < 4; ++n)                                            \
            acc[4 + m][n] = __builtin_amdgcn_mfma_f32_16x16x32_bf16(           \
                af[m], bfr[n], acc[4 + m][n], 0, 0, 0);                        \
    __builtin_amdgcn_s_setprio(0);                                             \
    __builtin_amdgcn_s_barrier();                                              \
  }

__global__ __launch_bounds__(512, 2) void main_gemm_kernel(
    const unsigned short* __restrict__ xb, const unsigned short* __restrict__ wb,
    const unsigned short* __restrict__ ub, const unsigned short* __restrict__ bt,
    const float* __restrict__ bias, const int* __restrict__ cu,
    float* __restrict__ out) {
    __shared__ __attribute__((aligned(1024))) char lds[131072];
    int tid  = threadIdx.x;
    int w    = tid >> 6, lane = tid & 63;
    int l15  = lane & 15, lk = lane >> 4;
    int wrow = (w >> 2) * 128;          // wave M-offset in tile
    int wcol = (w & 3) * 64;            // wave N-offset in tile
    // XCD-aware bijective swizzle: 512 blocks, 8 XCDs, 64 per XCD
    int swz  = (blockIdx.x & 7) * 64 + (blockIdx.x >> 3);
    int row0 = (swz >> 4) * 256;
    int col0 = (swz & 15) * 256;

    const unsigned short* xrow   = xb + (size_t)row0 * DIN;
    const unsigned short* wrow_g = wb + (size_t)col0 * DIN;

    f32x4 acc[8][4] = {};

    // prologue: stage K-tiles 0,1,2 (12 loads/thread), wait tile 0 (vmcnt 8)
    for (int pt = 0; pt < 3; ++pt) {
        int k0s = pt * 32;
        char* slot = lds + pt * 32768;
        stage_chunk(xrow + k0s, slot, 0, tid);
        stage_chunk(xrow + k0s, slot, 8192, tid);
        stage_chunk(wrow_g + k0s, slot + 16384, 0, tid);
        stage_chunk(wrow_g + k0s, slot + 16384, 8192, tid);
    }
    asm volatile("s_waitcnt vmcnt(8)" ::: "memory");
    __builtin_amdgcn_s_barrier();

    // main loop: 128 K-tiles; steady-state waits are vmcnt(8) (2 tiles in flight)
    #pragma unroll 1
    for (int t = 0; t < 125; ++t) KTILE_BODY(t, 1, 8);
    KTILE_BODY(125, 0, 4);
    KTILE_BODY(126, 0, 0);
    KTILE_BODY(127, 0, -1);

    // fused LoRA up-projection: one extra K=32 MFMA step per overlapping segment
    bf16x8 zero = {};
    for (int s = 0; s < NSEG; ++s) {
        int lo = cu[s], hi = cu[s + 1];
        if (hi <= row0 || lo >= row0 + 256) continue;
        bf16x8 au[8], bu[4];
        for (int m = 0; m < 8; ++m) {
            int row = row0 + wrow + m * 16 + l15;
            bf16x8 v = *(const bf16x8*)(ub + (size_t)row * 32 + lk * 8);
            au[m] = (row >= lo && row < hi) ? v : zero;
        }
        for (int n = 0; n < 4; ++n) {
            int col = col0 + wcol + n * 16 + l15;
            bu[n] = *(const bf16x8*)(bt + ((size_t)s * DOUT + col) * 32 + lk * 8);
        }
        for (int m = 0; m < 8; ++m)
            for (int n = 0; n < 4; ++n)
                acc[m][n] = __builtin_amdgcn_mfma_f32_16x16x32_bf16(
                    au[m], bu[n], acc[m][n], 0, 0, 0);
    }

    // epilogue: + bias, fp32 store
    float bv[4];
    for (int n = 0; n < 4; ++n) bv[n] = bias[col0 + wcol + n * 16 + l15];
    for (int m = 0; m < 8; ++m) {
        int rbase = row0 + wrow + m * 16 + lk * 4;
        for (int n = 0; n < 4; ++n) {
            int col = col0 + wcol + n * 16 + l15;
            for (int jj = 0; jj < 4; ++jj)
                out[(size_t)(rbase + jj) * DOUT + col] = acc[m][n][jj] + bv[n];
        }
    }
}

extern "C" void kernel_launch(void* const* d_in, const int* in_sizes, int n_in,
                              void* d_out, int out_size, void* d_ws, size_t ws_size,
                              hipStream_t stream) {
    const float* x  = (const float*)d_in[0];
    const float* W  = (const float*)d_in[1];
    const float* b  = (const float*)d_in[2];
    const float* lA = (const float*)d_in[3];
    const float* lB = (const float*)d_in[4];
    const int*   cu = (const int*)d_in[5];
    float* out = (float*)d_out;

    char* ws = (char*)d_ws;
    unsigned short* xb = (unsigned short*)(ws);                    // 64 MiB
    unsigned short* wb = (unsigned short*)(ws + 67108864);         // 32 MiB
    unsigned short* At = (unsigned short*)(ws + 100663296);        // 2 MiB
    unsigned short* Bt = (unsigned short*)(ws + 102760448);        // 2 MiB
    float*          Pu = (float*)(ws + 104857600);                 // 4 MiB
    unsigned short* ub = (unsigned short*)(ws + 109051904);        // 0.5 MiB

    cast_bf16_kernel<<<(T_TOK * DIN / 8) / 256, 256, 0, stream>>>(x, xb, T_TOK * DIN / 8);
    cast_bf16_kernel<<<(DOUT * DIN / 8) / 256, 256, 0, stream>>>(W, wb, DOUT * DIN / 8);
    prep_A_kernel<<<(NSEG * 32 * DIN) / 256, 256, 0, stream>>>(lA, At);
    prep_B_kernel<<<(NSEG * DOUT) / 256, 256, 0, stream>>>(lB, Bt);
    dim3 ug(T_TOK / 32, 4);
    u_gemm_kernel<<<ug, 64, 0, stream>>>(xb, At, cu, Pu);
    reduce_u_kernel<<<(T_TOK * 32) / 256, 256, 0, stream>>>(Pu, ub);
    dim3 mg(32 * 16);   // 512 tiles of 256x256
    main_gemm_kernel<<<mg, 512, 0, stream>>>(xb, wb, ub, Bt, b, cu, out);
}

// Round 4
// 326.618 us; speedup vs baseline: 1.0361x; 1.0361x over previous
//
#include <hip/hip_runtime.h>
#include <hip/hip_bf16.h>

// Problem constants (BLoraLinear): T=8192, D_IN=4096, D_OUT=4096, R=16, M=2, S=8
#define T_TOK 8192
#define DIN   4096
#define DOUT  4096
#define RANK  16
#define NMOD  2
#define NSEG  8

typedef __attribute__((ext_vector_type(8))) short bf16x8;
typedef __attribute__((ext_vector_type(8))) unsigned short u16x8;
typedef __attribute__((ext_vector_type(4))) float f32x4;

__device__ inline unsigned short f2bf(float f) {
    union { float f; unsigned u; } v; v.f = f;
    unsigned r = v.u + 0x7FFFu + ((v.u >> 16) & 1u);   // RNE
    return (unsigned short)(r >> 16);
}

__device__ inline void gload_lds16(const void* g, void* l) {
    __builtin_amdgcn_global_load_lds(
        (const __attribute__((address_space(1))) void*)g,
        (__attribute__((address_space(3))) void*)l, 16, 0, 0);
}

// ---------------- fp32 -> bf16 cast for x and W in one launch ----------------
__global__ void cast2_bf16_kernel(const float* __restrict__ sa,
                                  unsigned short* __restrict__ da, int n8a,
                                  const float* __restrict__ sb,
                                  unsigned short* __restrict__ db, int n8b) {
    int i = blockIdx.x * blockDim.x + threadIdx.x;
    const float* s;
    unsigned short* d;
    size_t j;
    if (i < n8a) { s = sa; d = da; j = (size_t)i; }
    else if (i < n8a + n8b) { s = sb; d = db; j = (size_t)(i - n8a); }
    else return;
    const float4* s4 = (const float4*)s;
    float4 a = s4[2 * j];
    float4 b = s4[2 * j + 1];
    u16x8 o;
    o[0] = f2bf(a.x); o[1] = f2bf(a.y); o[2] = f2bf(a.z); o[3] = f2bf(a.w);
    o[4] = f2bf(b.x); o[5] = f2bf(b.y); o[6] = f2bf(b.z); o[7] = f2bf(b.w);
    *(u16x8*)(d + 8 * j) = o;
}

// ---------- At[s][m*16+r][d] = lora_A[m][s][d][r]  (bf16) --------------------
__global__ void prep_A_kernel(const float* __restrict__ A,
                              unsigned short* __restrict__ At) {
    int idx = blockIdx.x * 256 + threadIdx.x;     // NSEG*32*DIN total
    int d   = idx & (DIN - 1);
    int smr = idx >> 12;
    int s   = smr >> 5, mr = smr & 31;
    int m   = mr >> 4,  r  = mr & 15;
    float v = A[(((size_t)(m * NSEG + s) * DIN) + d) * RANK + r];
    At[idx] = f2bf(v);
}

// ---------- Bt[s][o][m*16+r] = lora_B[m][s][r][o]  (bf16) --------------------
__global__ void prep_B_kernel(const float* __restrict__ B,
                              unsigned short* __restrict__ Bt) {
    int o  = blockIdx.x * 256 + threadIdx.x;      // NSEG*DOUT total
    int s  = o >> 12;
    int oc = o & (DOUT - 1);
    unsigned short tmp[32];
    for (int m = 0; m < NMOD; ++m)
        for (int r = 0; r < RANK; ++r)
            tmp[m * 16 + r] =
                f2bf(B[(((size_t)(m * NSEG + s) * RANK) + r) * DOUT + oc]);
    for (int k = 0; k < 4; ++k) {
        u16x8 v;
        for (int j = 0; j < 8; ++j) v[j] = tmp[k * 8 + j];
        *(u16x8*)(Bt + (size_t)o * 32 + k * 8) = v;
    }
}

// ---------- u partials: Pu[ky][t][mr] = sum_{k in split} x[t,k]*At[s(t)][mr][k]
__global__ __launch_bounds__(64) void u_gemm_kernel(
    const unsigned short* __restrict__ xb, const unsigned short* __restrict__ At,
    const int* __restrict__ cu, float* __restrict__ Pu) {
    int tile = blockIdx.x;          // 0..255
    int ky   = blockIdx.y;          // 0..3
    int lane = threadIdx.x;
    int l15  = lane & 15, lk = lane >> 4;
    int t0   = tile * 32;
    f32x4 acc[2][2] = {};
    bf16x8 zero = {};
    for (int s = 0; s < NSEG; ++s) {
        int lo = cu[s], hi = cu[s + 1];
        if (hi <= t0 || lo >= t0 + 32) continue;
        const unsigned short* atb = At + (size_t)(s * 32) * DIN;
        for (int kt = 0; kt < 32; ++kt) {
            int k0 = ky * 1024 + kt * 32 + lk * 8;
            bf16x8 a[2], b[2];
            for (int mi = 0; mi < 2; ++mi) {
                int row = t0 + mi * 16 + l15;
                bf16x8 av = *(const bf16x8*)(xb + (size_t)row * DIN + k0);
                a[mi] = (row >= lo && row < hi) ? av : zero;
            }
            for (int ni = 0; ni < 2; ++ni) {
                int mr = ni * 16 + l15;
                b[ni] = *(const bf16x8*)(atb + (size_t)mr * DIN + k0);
            }
            for (int mi = 0; mi < 2; ++mi)
                for (int ni = 0; ni < 2; ++ni)
                    acc[mi][ni] = __builtin_amdgcn_mfma_f32_16x16x32_bf16(
                        a[mi], b[ni], acc[mi][ni], 0, 0, 0);
        }
    }
    for (int mi = 0; mi < 2; ++mi)
        for (int ni = 0; ni < 2; ++ni)
            for (int j = 0; j < 4; ++j) {
                int t  = t0 + mi * 16 + lk * 4 + j;
                int mr = ni * 16 + l15;
                Pu[((size_t)ky * T_TOK + t) * 32 + mr] = acc[mi][ni][j];
            }
}

// ---------- reduce 4 K-split partials -> ub bf16 [T][32] ---------------------
__global__ void reduce_u_kernel(const float* __restrict__ Pu,
                                unsigned short* __restrict__ ub) {
    int idx = blockIdx.x * 256 + threadIdx.x;   // T_TOK*32
    const size_t STRIDE = (size_t)T_TOK * 32;
    float s = Pu[idx] + Pu[idx + STRIDE] + Pu[idx + 2 * STRIDE] + Pu[idx + 3 * STRIDE];
    ub[idx] = f2bf(s);
}

// ============================================================================
// Main GEMM: 256x256 tile, BK=32, 8 waves (2Mx4N), ring-of-4 LDS (128 KiB),
// prefetch distance 3 K-tiles, counted vmcnt(4) (never 0 in main loop),
// XOR-swizzled LDS (verified: SQ_LDS_BANK_CONFLICT = 0).
//
// Round-4 change: REGISTER READ-AHEAD-1. Each iteration t:
//   { ds_read af2(t) [4] + bfr/af(t+1) [8, into the OTHER reg set] ;
//     issue stage gloads (t+3) ; sched_barrier(0) ;
//     setprio(1) ; 32 MFMA on set read LAST iter (lgkm already satisfied,
//     so this iter's 12 reads drain on the LDS pipe UNDER the MFMA cluster) ;
//     setprio(0) ; vmcnt(4) ; s_barrier }
// Slot audit per barrier region: reads slots {t&3, (t+1)&3}, writes (t+3)&3
// -> disjoint mod 4; per-iter barrier bounds drift to < 1 iteration.
// ============================================================================

__device__ __forceinline__ bf16x8 lds_frag(const char* tile, int row, int lk) {
    int rb = (row << 6) + (lk << 4);
    rb ^= ((rb >> 7) & 7) << 4;
    return *(const bf16x8*)(tile + rb);
}

// stage one 8 KiB chunk (512 threads x 16 B) of a [256][32] bf16 tile half
__device__ __forceinline__ void stage_chunk(const unsigned short* gbase,
                                            char* lds_tile, int chunkbase, int tid) {
    int tb = chunkbase + tid * 16;
    int gb = tb ^ (((tb >> 7) & 7) << 4);
    int row = gb >> 6;
    int col = (gb & 63) >> 1;
    gload_lds16(gbase + (size_t)row * DIN + col, lds_tile + tb);
}

#define STAGE(T_)                                                              \
  {                                                                            \
    int k0s_ = (T_) * 32;                                                      \
    char* dst_ = lds + ((T_) & 3) * 32768;                                     \
    stage_chunk(xrow + k0s_, dst_, 0, tid);                                    \
    stage_chunk(xrow + k0s_, dst_, 8192, tid);                                 \
    stage_chunk(wrow_g + k0s_, dst_ + 16384, 0, tid);                          \
    stage_chunk(wrow_g + k0s_, dst_ + 16384, 8192, tid);                       \
  }

#define READ_AF2(T_)                                                           \
  {                                                                            \
    const char* Asl_ = lds + ((T_) & 3) * 32768;                               \
    for (int m = 0; m < 4; ++m)                                                \
        af2[m] = lds_frag(Asl_, wrow + (4 + m) * 16 + l15, lk);                \
  }

#define READ_MAIN(BFR_, AF_, T_)                                               \
  {                                                                            \
    const char* Asl_ = lds + ((T_) & 3) * 32768;                               \
    const char* Bsl_ = Asl_ + 16384;                                           \
    for (int n = 0; n < 4; ++n)                                                \
        BFR_[n] = lds_frag(Bsl_, wcol + n * 16 + l15, lk);                     \
    for (int m = 0; m < 4; ++m)                                                \
        AF_[m] = lds_frag(Asl_, wrow + m * 16 + l15, lk);                      \
  }

#define CLUSTER(BFR_, AF_)                                                     \
  {                                                                            \
    __builtin_amdgcn_s_setprio(1);                                             \
    for (int m = 0; m < 4; ++m)                                                \
        for (int n = 0; n < 4; ++n)                                            \
            acc[m][n] = __builtin_amdgcn_mfma_f32_16x16x32_bf16(               \
                AF_[m], BFR_[n], acc[m][n], 0, 0, 0);                          \
    for (int m = 0; m < 4; ++m)                                                \
        for (int n = 0; n < 4; ++n)                                            \
            acc[4 + m][n] = __builtin_amdgcn_mfma_f32_16x16x32_bf16(           \
                af2[m], BFR_[n], acc[4 + m][n], 0, 0, 0);                      \
    __builtin_amdgcn_s_setprio(0);                                             \
  }

// U*_ = operand set read last iter (tile T_); R*_ = set to fill for T_+1.
#define ITER(UB_, UA_, RB_, RA_, T_, STG_, VM_)                                \
  {                                                                            \
    READ_AF2(T_);                                                              \
    READ_MAIN(RB_, RA_, (T_) + 1);                                             \
    if (STG_) STAGE((T_) + 3);                                                 \
    __builtin_amdgcn_sched_barrier(0);                                         \
    CLUSTER(UB_, UA_);                                                         \
    if ((VM_) == 4)      asm volatile("s_waitcnt vmcnt(4)" ::: "memory");      \
    else if ((VM_) == 0) asm volatile("s_waitcnt vmcnt(0)" ::: "memory");      \
    if ((VM_) >= 0) __builtin_amdgcn_s_barrier();                              \
  }

__global__ __launch_bounds__(512, 2) void main_gemm_kernel(
    const unsigned short* __restrict__ xb, const unsigned short* __restrict__ wb,
    const unsigned short* __restrict__ ub, const unsigned short* __restrict__ bt,
    const float* __restrict__ bias, const int* __restrict__ cu,
    float* __restrict__ out) {
    __shared__ __attribute__((aligned(1024))) char lds[131072];
    int tid  = threadIdx.x;
    int w    = tid >> 6, lane = tid & 63;
    int l15  = lane & 15, lk = lane >> 4;
    int wrow = (w >> 2) * 128;          // wave M-offset in tile
    int wcol = (w & 3) * 64;            // wave N-offset in tile
    // XCD-aware bijective swizzle: 512 blocks, 8 XCDs, 64 per XCD
    int swz  = (blockIdx.x & 7) * 64 + (blockIdx.x >> 3);
    int row0 = (swz >> 4) * 256;
    int col0 = (swz & 15) * 256;

    const unsigned short* xrow   = xb + (size_t)row0 * DIN;
    const unsigned short* wrow_g = wb + (size_t)col0 * DIN;

    f32x4 acc[8][4] = {};
    bf16x8 bfrA[4], afA[4], bfrB[4], afB[4], af2[4];

    // prologue: stage K-tiles 0,1,2; vmcnt(4) -> tiles 0,1 resident
    STAGE(0); STAGE(1); STAGE(2);
    asm volatile("s_waitcnt vmcnt(4)" ::: "memory");
    __builtin_amdgcn_s_barrier();
    READ_MAIN(bfrA, afA, 0);

    // main loop, unrolled x2 with named register sets (no runtime indexing)
    #pragma unroll 1
    for (int t = 0; t < 124; t += 2) {
        ITER(bfrA, afA, bfrB, afB, t,     1, 4);
        ITER(bfrB, afB, bfrA, afA, t + 1, 1, 4);
    }
    // tail: t = 124..127
    ITER(bfrA, afA, bfrB, afB, 124, 1, 4);   // stages tile 127
    ITER(bfrB, afB, bfrA, afA, 125, 0, 0);   // vmcnt(0): tile 127 landed
    ITER(bfrA, afA, bfrB, afB, 126, 0, -1);  // no more barriers needed
    { READ_AF2(127); __builtin_amdgcn_sched_barrier(0); CLUSTER(bfrB, afB); }

    // fused LoRA up-projection: one extra K=32 MFMA step per overlapping segment
    bf16x8 zero = {};
    for (int s = 0; s < NSEG; ++s) {
        int lo = cu[s], hi = cu[s + 1];
        if (hi <= row0 || lo >= row0 + 256) continue;
        bf16x8 au[8], bu[4];
        for (int m = 0; m < 8; ++m) {
            int row = row0 + wrow + m * 16 + l15;
            bf16x8 v = *(const bf16x8*)(ub + (size_t)row * 32 + lk * 8);
            au[m] = (row >= lo && row < hi) ? v : zero;
        }
        for (int n = 0; n < 4; ++n) {
            int col = col0 + wcol + n * 16 + l15;
            bu[n] = *(const bf16x8*)(bt + ((size_t)s * DOUT + col) * 32 + lk * 8);
        }
        for (int m = 0; m < 8; ++m)
            for (int n = 0; n < 4; ++n)
                acc[m][n] = __builtin_amdgcn_mfma_f32_16x16x32_bf16(
                    au[m], bu[n], acc[m][n], 0, 0, 0);
    }

    // epilogue: + bias, fp32 store
    float bv[4];
    for (int n = 0; n < 4; ++n) bv[n] = bias[col0 + wcol + n * 16 + l15];
    for (int m = 0; m < 8; ++m) {
        int rbase = row0 + wrow + m * 16 + lk * 4;
        for (int n = 0; n < 4; ++n) {
            int col = col0 + wcol + n * 16 + l15;
            for (int jj = 0; jj < 4; ++jj)
                out[(size_t)(rbase + jj) * DOUT + col] = acc[m][n][jj] + bv[n];
        }
    }
}

extern "C" void kernel_launch(void* const* d_in, const int* in_sizes, int n_in,
                              void* d_out, int out_size, void* d_ws, size_t ws_size,
                              hipStream_t stream) {
    const float* x  = (const float*)d_in[0];
    const float* W  = (const float*)d_in[1];
    const float* b  = (const float*)d_in[2];
    const float* lA = (const float*)d_in[3];
    const float* lB = (const float*)d_in[4];
    const int*   cu = (const int*)d_in[5];
    float* out = (float*)d_out;

    char* ws = (char*)d_ws;
    unsigned short* xb = (unsigned short*)(ws);                    // 64 MiB
    unsigned short* wb = (unsigned short*)(ws + 67108864);         // 32 MiB
    unsigned short* At = (unsigned short*)(ws + 100663296);        // 2 MiB
    unsigned short* Bt = (unsigned short*)(ws + 102760448);        // 2 MiB
    float*          Pu = (float*)(ws + 104857600);                 // 4 MiB
    unsigned short* ub = (unsigned short*)(ws + 109051904);        // 0.5 MiB

    const int n8x = T_TOK * DIN / 8, n8w = DOUT * DIN / 8;
    cast2_bf16_kernel<<<(n8x + n8w) / 256, 256, 0, stream>>>(x, xb, n8x, W, wb, n8w);
    prep_A_kernel<<<(NSEG * 32 * DIN) / 256, 256, 0, stream>>>(lA, At);
    prep_B_kernel<<<(NSEG * DOUT) / 256, 256, 0, stream>>>(lB, Bt);
    dim3 ug(T_TOK / 32, 4);
    u_gemm_kernel<<<ug, 64, 0, stream>>>(xb, At, cu, Pu);
    reduce_u_kernel<<<(T_TOK * 32) / 256, 256, 0, stream>>>(Pu, ub);
    dim3 mg(32 * 16);   // 512 tiles of 256x256
    main_gemm_kernel<<<mg, 512, 0, stream>>>(xb, wb, ub, Bt, b, cu, out);
}